// Round 9
// baseline (131.825 us; speedup 1.0000x reference)
//
#include <hip/hip_runtime.h>
#include <cstdint>
#include <cstddef>

#define NEG_ (-1e25f)

typedef __bf16 bf16x8 __attribute__((ext_vector_type(8)));
typedef float  f32x4  __attribute__((ext_vector_type(4)));
typedef short  s16x8  __attribute__((ext_vector_type(8)));
typedef const __attribute__((address_space(1))) void* gas_t;
typedef __attribute__((address_space(3))) void* las_t;

#define MFMA16 __builtin_amdgcn_mfma_f32_16x16x32_bf16

__device__ __forceinline__ short f2bf(float f) {
  union { float f; unsigned u; } v; v.f = f;
  unsigned r = v.u + 0x7fffu + ((v.u >> 16) & 1u);  // RNE
  return (short)(r >> 16);
}

__device__ __forceinline__ s16x8 cvt8(const float* s) {
  bf16x8 r;
  #pragma unroll
  for (int j = 0; j < 8; ++j) r[j] = (__bf16)s[j];  // fptrunc = RNE
  union { bf16x8 b; s16x8 s; } u; u.b = r; return u.s;
}

__device__ __forceinline__ void gload(const short* g, short* l) {
  __builtin_amdgcn_global_load_lds((gas_t)g, (las_t)l, 16, 0, 0);
}

struct Params {
  const float* ment; const int* ents; const int* msk;
  const float* rm; const float* Wv; const float* bv; const float* Wu;
  const float* bu; const float* Wa; const float* Wr; const float* br;
  const float* Wo; const float* bo; float* out;
  short *Xb, *Wvb, *Wub, *rmb, *Wrb, *Wo2b, *swTb, *Ub, *Weffb, *erb;
  float *wpart, *cf, *gw2;
};

// ====== k0: one-pass f32 -> bf16 (X, Wv, Wu, rm, Wr, Wo2) ======
// 4,194,304 floats = 524288 vec8 units; 131072 threads -> 4 units each.
__global__ __launch_bounds__(256) void k0(Params p) {
  const int g = blockIdx.x * 256 + threadIdx.x;
  #pragma unroll
  for (int it = 0; it < 4; ++it) {
    int u = g + it * 131072;
    long e = (long)u * 8;
    const float* src; short* dst;
    if (u < 262144)      { src = p.ment + e;                     dst = p.Xb + e; }
    else if (u < 294912) { long o = e - 2097152; src = p.Wv + o; dst = p.Wvb + o; }
    else if (u < 327680) { long o = e - 2359296; src = p.Wu + o; dst = p.Wub + o; }
    else if (u < 393216) { long o = e - 2621440; src = p.rm + o; dst = p.rmb + o; }
    else if (u < 458752) { long o = e - 3145728; src = p.Wr + o; dst = p.Wrb + o; }
    else                 { long o = e - 3670016;
                           src = p.Wo + (o >> 9) * 1536 + 1024 + (o & 511);
                           dst = p.Wo2b + o; }
    float t[8];
    *(float4*)t       = *(const float4*)src;
    *(float4*)(t + 4) = *(const float4*)(src + 4);
    *(s16x8*)dst = cvt8(t);
  }
}

// ====== 64x64 bf16 GEMM: 6-buf ring, prefetch depth 4 (48 KB LDS) ======
__device__ void g64(const short* __restrict__ A, int lda,
                    const short* __restrict__ B, int ldb,
                    short* __restrict__ C, int ldc, int NT, int m0, int n0,
                    short* lds) {
  short* As = lds;            // 6 bufs * 2048 shorts (64x32)
  short* Bs = lds + 12288;
  const int tid = threadIdx.x, wave = tid >> 6, lane = tid & 63;
  const int quad = lane >> 4, l16 = lane & 15;
  const int wm = (wave & 1) * 32, wn = (wave >> 1) * 32;
  const int srow = tid >> 2, scol = (tid & 3) * 8;
  const short* Ag = A + (long)(m0 + srow) * lda + scol;
  const short* Bg = B + (long)(n0 + srow) * ldb + scol;
  const int wb = wave * 512;
  auto issue = [&](int kt) {
    int buf = kt % 6; int ko = kt * 32;
    gload(Ag + ko, As + buf * 2048 + wb);
    gload(Bg + ko, Bs + buf * 2048 + wb);
  };
  f32x4 acc[2][2] = {};
  issue(0); issue(1); issue(2); issue(3);
  for (int kt = 0; kt < NT; ++kt) {
    int rem = NT - 1 - kt;
    if (rem >= 3)      asm volatile("s_waitcnt vmcnt(6)" ::: "memory");
    else if (rem == 2) asm volatile("s_waitcnt vmcnt(4)" ::: "memory");
    else if (rem == 1) asm volatile("s_waitcnt vmcnt(2)" ::: "memory");
    else               asm volatile("s_waitcnt vmcnt(0)" ::: "memory");
    asm volatile("s_barrier" ::: "memory");
    if (kt + 4 < NT) issue(kt + 4);
    const short* as = As + (kt % 6) * 2048;
    const short* bs = Bs + (kt % 6) * 2048;
    bf16x8 a0 = *(const bf16x8*)&as[(wm + l16) * 32 + quad * 8];
    bf16x8 a1 = *(const bf16x8*)&as[(wm + 16 + l16) * 32 + quad * 8];
    bf16x8 b0 = *(const bf16x8*)&bs[(wn + l16) * 32 + quad * 8];
    bf16x8 b1 = *(const bf16x8*)&bs[(wn + 16 + l16) * 32 + quad * 8];
    acc[0][0] = MFMA16(a0, b0, acc[0][0], 0, 0, 0);
    acc[0][1] = MFMA16(a0, b1, acc[0][1], 0, 0, 0);
    acc[1][0] = MFMA16(a1, b0, acc[1][0], 0, 0, 0);
    acc[1][1] = MFMA16(a1, b1, acc[1][1], 0, 0, 0);
  }
  #pragma unroll
  for (int i = 0; i < 2; ++i)
    #pragma unroll
    for (int j = 0; j < 2; ++j) {
      int col = n0 + wn + j * 16 + l16;
      #pragma unroll
      for (int r = 0; r < 4; ++r) {
        int row = m0 + wm + i * 16 + quad * 4 + r;
        C[(long)row * ldc + col] = f2bf(acc[i][j][r]);
      }
    }
}

// ====== 64x32 bf16 GEMM: 6-buf ring depth 4, 36 KB LDS -> 4 blocks/CU ======
// Waves 2x2 over 32(M)x16(N); waves 0-1 also stage B (2 loads/iter vs 1).
// EPI 1: C bf16 = acc + e0[row*1536+col] (f32 Wo1, coalesced 128B rows).
// EPI 2: C f32 = acc + e0[col] + e1[row]*e2[col].
template <int NT, int EPI>
__device__ void g6432(const short* __restrict__ A, int lda,
                      const short* __restrict__ B, int ldb,
                      void* __restrict__ C, int ldc, int m0, int n0,
                      const float* __restrict__ e0, const float* __restrict__ e1,
                      const float* __restrict__ e2, short* lds) {
  short* As = lds;            // 6 bufs * 2048 shorts (64x32)
  short* Bs = lds + 12288;    // 6 bufs * 1024 shorts (32x32)
  const int tid = threadIdx.x, wave = tid >> 6, lane = tid & 63;
  const int quad = lane >> 4, l16 = lane & 15;
  const int wm = (wave & 1) * 32, wn = (wave >> 1) * 16;
  const int srow = tid >> 2, scol = (tid & 3) * 8;
  const short* Ag = A + (long)(m0 + srow) * lda + scol;
  const short* Bg = B + (long)(n0 + srow) * ldb + scol;  // valid tid<128
  const int wb = wave * 512;
  auto issue = [&](int kt) {
    int buf = kt % 6; int ko = kt * 32;
    gload(Ag + ko, As + buf * 2048 + wb);
    if (tid < 128) gload(Bg + ko, Bs + buf * 1024 + wb);
  };
  f32x4 acc[2] = {};
  issue(0); issue(1); issue(2); issue(3);
  for (int kt = 0; kt < NT; ++kt) {
    int rem = NT - 1 - kt;
    if (wave < 2) {  // 2 loads/iter
      if (rem >= 3)      asm volatile("s_waitcnt vmcnt(6)" ::: "memory");
      else if (rem == 2) asm volatile("s_waitcnt vmcnt(4)" ::: "memory");
      else if (rem == 1) asm volatile("s_waitcnt vmcnt(2)" ::: "memory");
      else               asm volatile("s_waitcnt vmcnt(0)" ::: "memory");
    } else {         // 1 load/iter
      if (rem >= 3)      asm volatile("s_waitcnt vmcnt(3)" ::: "memory");
      else if (rem == 2) asm volatile("s_waitcnt vmcnt(2)" ::: "memory");
      else if (rem == 1) asm volatile("s_waitcnt vmcnt(1)" ::: "memory");
      else               asm volatile("s_waitcnt vmcnt(0)" ::: "memory");
    }
    asm volatile("s_barrier" ::: "memory");
    if (kt + 4 < NT) issue(kt + 4);
    const short* as = As + (kt % 6) * 2048;
    const short* bs = Bs + (kt % 6) * 1024;
    bf16x8 a0 = *(const bf16x8*)&as[(wm + l16) * 32 + quad * 8];
    bf16x8 a1 = *(const bf16x8*)&as[(wm + 16 + l16) * 32 + quad * 8];
    bf16x8 b0 = *(const bf16x8*)&bs[(wn + l16) * 32 + quad * 8];
    acc[0] = MFMA16(a0, b0, acc[0], 0, 0, 0);
    acc[1] = MFMA16(a1, b0, acc[1], 0, 0, 0);
  }
  #pragma unroll
  for (int i = 0; i < 2; ++i) {
    int col = n0 + wn + l16;
    #pragma unroll
    for (int r = 0; r < 4; ++r) {
      int row = m0 + wm + i * 16 + quad * 4 + r;
      float v = acc[i][r];
      if constexpr (EPI == 1) {
        v += e0[(long)row * 1536 + col];
        ((short*)C)[(long)row * ldc + col] = f2bf(v);
      } else {
        v += e0[col] + e1[row] * e2[col];
        ((float*)C)[(long)row * ldc + col] = v;
      }
    }
  }
}

// ====== vu gate 32(M)x64(N), 5-buf ring depth 4 (50 KB LDS) ======
__device__ void vu_ring(int mi, int ni, const Params& p, short* lds, float* red) {
  short* As  = lds;                        // 5 bufs * 1024 shorts (32x32)
  short* Bvs = lds + 5 * 1024;             // 5 bufs * 2048 (64x32)
  short* Bus = lds + 5 * 1024 + 5 * 2048;  // 5 bufs * 2048
  const int tid = threadIdx.x, wave = tid >> 6, lane = tid & 63;
  const int quad = lane >> 4, l16 = lane & 15;
  const int wm = (wave & 1) * 16, wn = (wave >> 1) * 32;
  const int m0 = mi * 32, n0 = ni * 64;
  const int srow = tid >> 2, scol = (tid & 3) * 8;
  const short* Ag  = p.Xb  + (long)(m0 + srow) * 1024 + scol;  // waves 0-1 only
  const short* Bvg = p.Wvb + (long)(n0 + srow) * 1024 + scol;
  const short* Bug = p.Wub + (long)(n0 + srow) * 1024 + scol;
  const int wb = wave * 512;
  auto issue = [&](int kt) {
    int buf = kt % 5; int ko = kt * 32;
    if (wave < 2)
      gload(Ag + ko, As + buf * 1024 + wb);
    gload(Bvg + ko, Bvs + buf * 2048 + wb);
    gload(Bug + ko, Bus + buf * 2048 + wb);
  };
  f32x4 accv[2] = {}, accu[2] = {};
  issue(0); issue(1); issue(2); issue(3);
  for (int kt = 0; kt < 32; ++kt) {
    int rem = 31 - kt;
    if (wave < 2) {  // 3 loads/iter
      if (rem >= 3)      asm volatile("s_waitcnt vmcnt(9)" ::: "memory");
      else if (rem == 2) asm volatile("s_waitcnt vmcnt(6)" ::: "memory");
      else if (rem == 1) asm volatile("s_waitcnt vmcnt(3)" ::: "memory");
      else               asm volatile("s_waitcnt vmcnt(0)" ::: "memory");
    } else {         // 2 loads/iter
      if (rem >= 3)      asm volatile("s_waitcnt vmcnt(6)" ::: "memory");
      else if (rem == 2) asm volatile("s_waitcnt vmcnt(4)" ::: "memory");
      else if (rem == 1) asm volatile("s_waitcnt vmcnt(2)" ::: "memory");
      else               asm volatile("s_waitcnt vmcnt(0)" ::: "memory");
    }
    asm volatile("s_barrier" ::: "memory");
    if (kt + 4 < 32) issue(kt + 4);
    const short* as  = As  + (kt % 5) * 1024;
    const short* bvs = Bvs + (kt % 5) * 2048;
    const short* bus = Bus + (kt % 5) * 2048;
    bf16x8 af = *(const bf16x8*)&as[(wm + l16) * 32 + quad * 8];
    bf16x8 v0 = *(const bf16x8*)&bvs[(wn + l16) * 32 + quad * 8];
    bf16x8 v1 = *(const bf16x8*)&bvs[(wn + 16 + l16) * 32 + quad * 8];
    bf16x8 u0 = *(const bf16x8*)&bus[(wn + l16) * 32 + quad * 8];
    bf16x8 u1 = *(const bf16x8*)&bus[(wn + 16 + l16) * 32 + quad * 8];
    accv[0] = MFMA16(af, v0, accv[0], 0, 0, 0);
    accv[1] = MFMA16(af, v1, accv[1], 0, 0, 0);
    accu[0] = MFMA16(af, u0, accu[0], 0, 0, 0);
    accu[1] = MFMA16(af, u1, accu[1], 0, 0, 0);
  }
  float wsum[4] = {0.f, 0.f, 0.f, 0.f};
  #pragma unroll
  for (int j = 0; j < 2; ++j) {
    int col = n0 + wn + j * 16 + l16;
    float bvc = p.bv[col], buc = p.bu[col], wac = p.Wa[col];
    #pragma unroll
    for (int r = 0; r < 4; ++r) {
      float vv = tanhf(accv[j][r] + bvc);
      float uu = accu[j][r] + buc;
      wsum[r] += (vv / (1.0f + expf(-uu))) * wac;
    }
  }
  #pragma unroll
  for (int r = 0; r < 4; ++r) {
    float s = wsum[r];
    s += __shfl_down(s, 8, 16);
    s += __shfl_down(s, 4, 16);
    s += __shfl_down(s, 2, 16);
    s += __shfl_down(s, 1, 16);
    if (l16 == 0) red[(wave >> 1) * 32 + wm + quad * 4 + r] = s;
  }
  __syncthreads();
  if (tid < 32) p.wpart[ni * 2048 + m0 + tid] = red[tid] + red[32 + tid];
}

// ---- gw2 rowsum, one row per wave ----
__device__ void gw2_wave(int row, const Params& p) {
  const int lane = threadIdx.x & 63;
  const short* u = p.Ub + (long)row * 1024 + lane * 16;
  union { s16x8 s; bf16x8 b; } w0, w1;
  w0.s = *(const s16x8*)u;
  w1.s = *(const s16x8*)(u + 8);
  float s = 0.f;
  #pragma unroll
  for (int j = 0; j < 8; ++j) s += (float)w0.b[j] + (float)w1.b[j];
  #pragma unroll
  for (int off = 32; off > 0; off >>= 1) s += __shfl_down(s, off);
  if (lane == 0) p.gw2[row] = s;
}

// ---- masked softmax K=16 + pooling, ONE WAVE per entity, bf16 X gather ----
__device__ void entity_wave(int be, const Params& p) {
  const int lane = threadIdx.x & 63;
  const int b = be >> 7;  // E=128
  float a = NEG_; int idx = 0;
  if (lane < 16) {
    idx = p.ents[be * 16 + lane];
    int j = (b << 8) + idx;
    float lw = p.wpart[j] + p.wpart[2048 + j] + p.wpart[4096 + j] + p.wpart[6144 + j];
    a = p.msk[be * 16 + lane] ? lw : NEG_;
  }
  float m = a;
  m = fmaxf(m, __shfl_xor(m, 1, 16));
  m = fmaxf(m, __shfl_xor(m, 2, 16));
  m = fmaxf(m, __shfl_xor(m, 4, 16));
  m = fmaxf(m, __shfl_xor(m, 8, 16));
  float e = expf(a - m);
  float s = e;
  s += __shfl_xor(s, 1, 16);
  s += __shfl_xor(s, 2, 16);
  s += __shfl_xor(s, 4, 16);
  s += __shfl_xor(s, 8, 16);
  float aw = e / s;  // valid on lanes 0-15
  float ak[16]; int ik[16];
  #pragma unroll
  for (int k = 0; k < 16; ++k) { ak[k] = __shfl(aw, k); ik[k] = __shfl(idx, k); }
  const short* Xr = p.Xb + ((long)b << 18);
  const int h0 = lane * 16;
  float acc[16];
  #pragma unroll
  for (int t = 0; t < 16; ++t) acc[t] = 0.f;
  #pragma unroll
  for (int c = 0; c < 2; ++c) {
    s16x8 xv[8][2];
    #pragma unroll
    for (int k = 0; k < 8; ++k) {
      const short* xr = Xr + (long)ik[c * 8 + k] * 1024 + h0;
      xv[k][0] = *(const s16x8*)xr;
      xv[k][1] = *(const s16x8*)(xr + 8);
    }
    #pragma unroll
    for (int k = 0; k < 8; ++k) {
      union { s16x8 s; bf16x8 b; } u0, u1;
      u0.s = xv[k][0]; u1.s = xv[k][1];
      float akk = ak[c * 8 + k];
      #pragma unroll
      for (int t = 0; t < 8; ++t) {
        acc[t]     += akk * (float)u0.b[t];
        acc[8 + t] += akk * (float)u1.b[t];
      }
    }
  }
  short* er = p.erb + (long)be * 1024 + h0;
  *(s16x8*)er       = cvt8(acc);
  *(s16x8*)(er + 8) = cvt8(acc + 8);
  float c = 0.f;
  const float* brp = p.br + h0;
  #pragma unroll
  for (int t = 0; t < 16; ++t) c += acc[t] * brp[t];
  #pragma unroll
  for (int off = 32; off > 0; off >>= 1) c += __shfl_down(c, off);
  if (lane == 0) p.cf[be] = c;
}

// == k1: vu gate (0-255) | s_wT (256-511) | U (512-767) — 768 = 3/CU x 256 ==
__global__ __launch_bounds__(256) void k1(Params p) {
  __shared__ short lds[25600];   // 50 KB (vu: 50 KB; g64: 48 KB)
  __shared__ float red[64];
  const int blk = blockIdx.x;
  if (blk < 256) {
    vu_ring(blk & 63, blk >> 6, p, lds, red);
  } else if (blk < 512) {
    int q = blk - 256;
    g64(p.Wrb, 512, p.rmb, 512, p.swTb, 1024, 16,
        (q >> 4) * 64, (q & 15) * 64, lds);
  } else {
    int q = blk - 512;
    g64(p.Wo2b, 512, p.rmb, 512, p.Ub, 1024, 16,
        (q >> 4) * 64, (q & 15) * 64, lds);
  }
}

// ==== k2: Weff = Wo1 + U@s_wT^T (0-511, 64x32) | gw2 + softmax (512-767) ====
__global__ __launch_bounds__(256) void k2(Params p) {
  __shared__ short lds[18432];   // 36 KB -> 4 blocks/CU
  const int blk = blockIdx.x;
  if (blk < 512) {
    g6432<32, 1>(p.Ub, 1024, p.swTb, 1024, p.Weffb, 1024,
                 (blk >> 5) * 64, (blk & 31) * 32, p.Wo, nullptr, nullptr, lds);
  } else {
    int q = blk - 512;
    int wave = threadIdx.x >> 6;
    gw2_wave(q * 4 + wave, p);
    entity_wave(q * 4 + wave, p);
  }
}

// ======= k3: out = er @ Weff^T + bo + cf*gw2 (512 blocks, 64x32) =======
__global__ __launch_bounds__(256) void k3(Params p) {
  __shared__ short lds[18432];
  const int blk = blockIdx.x;
  g6432<32, 2>(p.erb, 1024, p.Weffb, 1024, p.out, 1024,
               (blk >> 5) * 64, (blk & 31) * 32, p.bo, p.cf, p.gw2, lds);
}

extern "C" void kernel_launch(void* const* d_in, const int* in_sizes, int n_in,
                              void* d_out, int out_size, void* d_ws, size_t ws_size,
                              hipStream_t stream) {
  (void)in_sizes; (void)n_in; (void)out_size; (void)ws_size;
  Params p;
  p.ment = (const float*)d_in[0];
  p.ents = (const int*)d_in[1];
  p.msk  = (const int*)d_in[2];
  p.rm   = (const float*)d_in[3];
  p.Wv   = (const float*)d_in[4];
  p.bv   = (const float*)d_in[5];
  p.Wu   = (const float*)d_in[6];
  p.bu   = (const float*)d_in[7];
  p.Wa   = (const float*)d_in[8];
  // d_in[9] = ba: drops out (softmax shift-invariance)
  p.Wr   = (const float*)d_in[10];
  p.br   = (const float*)d_in[11];
  p.Wo   = (const float*)d_in[12];
  p.bo   = (const float*)d_in[13];
  p.out  = (float*)d_out;

  char* w = (char*)d_ws;
  auto alloc = [&](size_t bytes) {
    void* q = (void*)w; w += (bytes + 255) & ~(size_t)255; return q;
  };
  p.Xb    = (short*)alloc((size_t)2048 * 1024 * 2);  // X bf16
  p.Wvb   = (short*)alloc((size_t)256 * 1024 * 2);
  p.Wub   = (short*)alloc((size_t)256 * 1024 * 2);
  p.rmb   = (short*)alloc((size_t)1024 * 512 * 2);
  p.Wrb   = (short*)alloc((size_t)1024 * 512 * 2);
  p.Wo2b  = (short*)alloc((size_t)1024 * 512 * 2);
  p.swTb  = (short*)alloc((size_t)1024 * 1024 * 2);  // s_wT[h,r] bf16
  p.Ub    = (short*)alloc((size_t)1024 * 1024 * 2);  // U[h,r] bf16
  p.Weffb = (short*)alloc((size_t)1024 * 1024 * 2);  // Wo1 + U@s_wT^T bf16
  p.erb   = (short*)alloc((size_t)1024 * 1024 * 2);  // entity reprs bf16
  p.wpart = (float*)alloc((size_t)4 * 2048 * 4);     // gate partials
  p.cf    = (float*)alloc((size_t)1024 * 4);         // er . br
  p.gw2   = (float*)alloc((size_t)1024 * 4);         // rowsum(U)

  k0<<<512, 256, 0, stream>>>(p);
  k1<<<768, 256, 0, stream>>>(p);
  k2<<<768, 256, 0, stream>>>(p);
  k3<<<512, 256, 0, stream>>>(p);
}

// Round 11
// 130.547 us; speedup vs baseline: 1.0098x; 1.0098x over previous
//
#include <hip/hip_runtime.h>
#include <cstdint>
#include <cstddef>

#define NEG_ (-1e25f)

typedef __bf16 bf16x8 __attribute__((ext_vector_type(8)));
typedef float  f32x4  __attribute__((ext_vector_type(4)));
typedef short  s16x8  __attribute__((ext_vector_type(8)));
typedef const __attribute__((address_space(1))) void* gas_t;
typedef __attribute__((address_space(3))) void* las_t;

#define MFMA16 __builtin_amdgcn_mfma_f32_16x16x32_bf16

__device__ __forceinline__ short f2bf(float f) {
  union { float f; unsigned u; } v; v.f = f;
  unsigned r = v.u + 0x7fffu + ((v.u >> 16) & 1u);  // RNE
  return (short)(r >> 16);
}

__device__ __forceinline__ float bf2f(short s) {
  union { unsigned u; float f; } t; t.u = ((unsigned)(unsigned short)s) << 16;
  return t.f;
}

__device__ __forceinline__ s16x8 cvt8(const float* s) {
  bf16x8 r;
  #pragma unroll
  for (int j = 0; j < 8; ++j) r[j] = (__bf16)s[j];  // fptrunc = RNE
  union { bf16x8 b; s16x8 s; } u; u.b = r; return u.s;
}

__device__ __forceinline__ void gload(const short* g, short* l) {
  __builtin_amdgcn_global_load_lds((gas_t)g, (las_t)l, 16, 0, 0);
}

struct Params {
  const float* ment; const int* ents; const int* msk;
  const float* rm; const float* Wv; const float* bv; const float* Wu;
  const float* bu; const float* Wa; const float* Wr; const float* br;
  const float* Wo; const float* bo; float* out;
  short *Xb, *Wvb, *Wub, *rmb, *Wrb, *Wo2b, *Wo1b, *swTb, *Ub, *Weffb, *erb;
  float *wpart, *cf, *gw2;
};

// ====== k0: one-pass f32 -> bf16 (X, Wv, Wu, rm, Wr, Wo2; Wo1 moved to k1) ==
// 4,194,304 floats = 524288 vec8 units; 131072 threads -> 4 units each.
__global__ __launch_bounds__(256) void k0(Params p) {
  const int g = blockIdx.x * 256 + threadIdx.x;
  #pragma unroll
  for (int it = 0; it < 4; ++it) {
    int u = g + it * 131072;
    long e = (long)u * 8;
    const float* src; short* dst;
    if (u < 262144)      { src = p.ment + e;                     dst = p.Xb + e; }
    else if (u < 294912) { long o = e - 2097152; src = p.Wv + o; dst = p.Wvb + o; }
    else if (u < 327680) { long o = e - 2359296; src = p.Wu + o; dst = p.Wub + o; }
    else if (u < 393216) { long o = e - 2621440; src = p.rm + o; dst = p.rmb + o; }
    else if (u < 458752) { long o = e - 3145728; src = p.Wr + o; dst = p.Wrb + o; }
    else                 { long o = e - 3670016;
                           src = p.Wo + (o >> 9) * 1536 + 1024 + (o & 511);
                           dst = p.Wo2b + o; }
    float t[8];
    *(float4*)t       = *(const float4*)src;
    *(float4*)(t + 4) = *(const float4*)(src + 4);
    *(s16x8*)dst = cvt8(t);
  }
}

// ====== 64x64 bf16 GEMM, DEEP ring: 8 bufs, prefetch depth 6 ======
template <int NT, int EPI>
__device__ void g64(const short* __restrict__ A, int lda,
                    const short* __restrict__ B, int ldb,
                    void* __restrict__ C, int ldc, int m0, int n0,
                    const short* __restrict__ w1, const float* __restrict__ e0,
                    const float* __restrict__ e1, const float* __restrict__ e2,
                    short* lds) {
  short* As = lds;            // 8 bufs * 2048 shorts (64x32)
  short* Bs = lds + 16384;
  const int tid = threadIdx.x, wave = tid >> 6, lane = tid & 63;
  const int quad = lane >> 4, l16 = lane & 15;
  const int wm = (wave & 1) * 32, wn = (wave >> 1) * 32;
  const int srow = tid >> 2, scol = (tid & 3) * 8;
  const short* Ag = A + (long)(m0 + srow) * lda + scol;
  const short* Bg = B + (long)(n0 + srow) * ldb + scol;
  const int wb = wave * 512;
  auto issue = [&](int kt) {
    int buf = kt & 7; int ko = kt * 32;
    gload(Ag + ko, As + buf * 2048 + wb);
    gload(Bg + ko, Bs + buf * 2048 + wb);
  };
  f32x4 acc[2][2] = {};
  issue(0); issue(1); issue(2); issue(3); issue(4); issue(5);
  for (int kt = 0; kt < NT; ++kt) {
    int rem = NT - 1 - kt;
    if (rem >= 5)      asm volatile("s_waitcnt vmcnt(10)" ::: "memory");
    else if (rem == 4) asm volatile("s_waitcnt vmcnt(8)" ::: "memory");
    else if (rem == 3) asm volatile("s_waitcnt vmcnt(6)" ::: "memory");
    else if (rem == 2) asm volatile("s_waitcnt vmcnt(4)" ::: "memory");
    else if (rem == 1) asm volatile("s_waitcnt vmcnt(2)" ::: "memory");
    else               asm volatile("s_waitcnt vmcnt(0)" ::: "memory");
    asm volatile("s_barrier" ::: "memory");
    if (kt + 6 < NT) issue(kt + 6);
    const short* as = As + (kt & 7) * 2048;
    const short* bs = Bs + (kt & 7) * 2048;
    bf16x8 a0 = *(const bf16x8*)&as[(wm + l16) * 32 + quad * 8];
    bf16x8 a1 = *(const bf16x8*)&as[(wm + 16 + l16) * 32 + quad * 8];
    bf16x8 b0 = *(const bf16x8*)&bs[(wn + l16) * 32 + quad * 8];
    bf16x8 b1 = *(const bf16x8*)&bs[(wn + 16 + l16) * 32 + quad * 8];
    acc[0][0] = MFMA16(a0, b0, acc[0][0], 0, 0, 0);
    acc[0][1] = MFMA16(a0, b1, acc[0][1], 0, 0, 0);
    acc[1][0] = MFMA16(a1, b0, acc[1][0], 0, 0, 0);
    acc[1][1] = MFMA16(a1, b1, acc[1][1], 0, 0, 0);
  }
  #pragma unroll
  for (int i = 0; i < 2; ++i)
    #pragma unroll
    for (int j = 0; j < 2; ++j) {
      int col = n0 + wn + j * 16 + l16;
      #pragma unroll
      for (int r = 0; r < 4; ++r) {
        int row = m0 + wm + i * 16 + quad * 4 + r;
        float v = acc[i][j][r];
        if constexpr (EPI == 0) {
          ((short*)C)[(long)row * ldc + col] = f2bf(v);
        } else if constexpr (EPI == 1) {
          v += bf2f(w1[(long)row * 1024 + col]);
          ((short*)C)[(long)row * ldc + col] = f2bf(v);
        } else {
          v += e0[col] + e1[row] * e2[col];
          ((float*)C)[(long)row * ldc + col] = v;
        }
      }
    }
}

// ====== vu gate 32(M)x64(N), deep ring: 6 bufs, prefetch depth 4 ======
// waves 0-1: 3 loads/iter; waves 2-3: 2 loads/iter.
__device__ void vu_ring(int mi, int ni, const Params& p, short* lds, float* red) {
  short* As  = lds;                        // 6 bufs * 1024 shorts (32x32)
  short* Bvs = lds + 6 * 1024;             // 6 bufs * 2048 (64x32)
  short* Bus = lds + 6 * 1024 + 6 * 2048;  // 6 bufs * 2048
  const int tid = threadIdx.x, wave = tid >> 6, lane = tid & 63;
  const int quad = lane >> 4, l16 = lane & 15;
  const int wm = (wave & 1) * 16, wn = (wave >> 1) * 32;
  const int m0 = mi * 32, n0 = ni * 64;
  const int srow = tid >> 2, scol = (tid & 3) * 8;
  const short* Ag  = p.Xb  + (long)(m0 + srow) * 1024 + scol;  // waves 0-1 only
  const short* Bvg = p.Wvb + (long)(n0 + srow) * 1024 + scol;
  const short* Bug = p.Wub + (long)(n0 + srow) * 1024 + scol;
  const int wb = wave * 512;
  auto issue = [&](int kt) {
    int buf = kt % 6; int ko = kt * 32;
    if (wave < 2)
      gload(Ag + ko, As + buf * 1024 + wb);
    gload(Bvg + ko, Bvs + buf * 2048 + wb);
    gload(Bug + ko, Bus + buf * 2048 + wb);
  };
  f32x4 accv[2] = {}, accu[2] = {};
  issue(0); issue(1); issue(2); issue(3);
  for (int kt = 0; kt < 32; ++kt) {
    int rem = 31 - kt;
    if (wave < 2) {  // 3 loads/iter
      if (rem >= 3)      asm volatile("s_waitcnt vmcnt(9)" ::: "memory");
      else if (rem == 2) asm volatile("s_waitcnt vmcnt(6)" ::: "memory");
      else if (rem == 1) asm volatile("s_waitcnt vmcnt(3)" ::: "memory");
      else               asm volatile("s_waitcnt vmcnt(0)" ::: "memory");
    } else {         // 2 loads/iter
      if (rem >= 3)      asm volatile("s_waitcnt vmcnt(6)" ::: "memory");
      else if (rem == 2) asm volatile("s_waitcnt vmcnt(4)" ::: "memory");
      else if (rem == 1) asm volatile("s_waitcnt vmcnt(2)" ::: "memory");
      else               asm volatile("s_waitcnt vmcnt(0)" ::: "memory");
    }
    asm volatile("s_barrier" ::: "memory");
    if (kt + 4 < 32) issue(kt + 4);
    const short* as  = As  + (kt % 6) * 1024;
    const short* bvs = Bvs + (kt % 6) * 2048;
    const short* bus = Bus + (kt % 6) * 2048;
    bf16x8 af = *(const bf16x8*)&as[(wm + l16) * 32 + quad * 8];
    bf16x8 v0 = *(const bf16x8*)&bvs[(wn + l16) * 32 + quad * 8];
    bf16x8 v1 = *(const bf16x8*)&bvs[(wn + 16 + l16) * 32 + quad * 8];
    bf16x8 u0 = *(const bf16x8*)&bus[(wn + l16) * 32 + quad * 8];
    bf16x8 u1 = *(const bf16x8*)&bus[(wn + 16 + l16) * 32 + quad * 8];
    accv[0] = MFMA16(af, v0, accv[0], 0, 0, 0);
    accv[1] = MFMA16(af, v1, accv[1], 0, 0, 0);
    accu[0] = MFMA16(af, u0, accu[0], 0, 0, 0);
    accu[1] = MFMA16(af, u1, accu[1], 0, 0, 0);
  }
  float wsum[4] = {0.f, 0.f, 0.f, 0.f};
  #pragma unroll
  for (int j = 0; j < 2; ++j) {
    int col = n0 + wn + j * 16 + l16;
    float bvc = p.bv[col], buc = p.bu[col], wac = p.Wa[col];
    #pragma unroll
    for (int r = 0; r < 4; ++r) {
      float vv = tanhf(accv[j][r] + bvc);
      float uu = accu[j][r] + buc;
      wsum[r] += (vv / (1.0f + expf(-uu))) * wac;
    }
  }
  #pragma unroll
  for (int r = 0; r < 4; ++r) {
    float s = wsum[r];
    s += __shfl_down(s, 8, 16);
    s += __shfl_down(s, 4, 16);
    s += __shfl_down(s, 2, 16);
    s += __shfl_down(s, 1, 16);
    if (l16 == 0) red[(wave >> 1) * 32 + wm + quad * 4 + r] = s;
  }
  __syncthreads();
  if (tid < 32) p.wpart[ni * 2048 + m0 + tid] = red[tid] + red[32 + tid];
}

// ---- gw2 rowsum, one row per wave ----
__device__ void gw2_wave(int row, const Params& p) {
  const int lane = threadIdx.x & 63;
  const short* u = p.Ub + (long)row * 1024 + lane * 16;
  union { s16x8 s; bf16x8 b; } w0, w1;
  w0.s = *(const s16x8*)u;
  w1.s = *(const s16x8*)(u + 8);
  float s = 0.f;
  #pragma unroll
  for (int j = 0; j < 8; ++j) s += (float)w0.b[j] + (float)w1.b[j];
  #pragma unroll
  for (int off = 32; off > 0; off >>= 1) s += __shfl_down(s, off);
  if (lane == 0) p.gw2[row] = s;
}

// ---- masked softmax K=16 + pooling, ONE WAVE per entity, bf16 X gather ----
// Gathers from Xb (bf16): half the line volume of f32 ment; loads batched
// 8 rows deep (16 outstanding 16B loads) for MLP instead of serial chain.
__device__ void entity_wave(int be, const Params& p) {
  const int lane = threadIdx.x & 63;
  const int b = be >> 7;  // E=128
  float a = NEG_; int idx = 0;
  if (lane < 16) {
    idx = p.ents[be * 16 + lane];
    int j = (b << 8) + idx;
    float lw = p.wpart[j] + p.wpart[2048 + j] + p.wpart[4096 + j] + p.wpart[6144 + j];
    a = p.msk[be * 16 + lane] ? lw : NEG_;
  }
  float m = a;
  m = fmaxf(m, __shfl_xor(m, 1, 16));
  m = fmaxf(m, __shfl_xor(m, 2, 16));
  m = fmaxf(m, __shfl_xor(m, 4, 16));
  m = fmaxf(m, __shfl_xor(m, 8, 16));
  float e = expf(a - m);
  float s = e;
  s += __shfl_xor(s, 1, 16);
  s += __shfl_xor(s, 2, 16);
  s += __shfl_xor(s, 4, 16);
  s += __shfl_xor(s, 8, 16);
  float aw = e / s;  // valid on lanes 0-15
  // hoist all (a_k, idx_k) first — removes the shuffle from the load loop
  float ak[16]; int ik[16];
  #pragma unroll
  for (int k = 0; k < 16; ++k) { ak[k] = __shfl(aw, k); ik[k] = __shfl(idx, k); }
  const short* Xr = p.Xb + ((long)b << 18);  // 256*1024 bf16 per batch
  const int h0 = lane * 16;
  float acc[16];
  #pragma unroll
  for (int t = 0; t < 16; ++t) acc[t] = 0.f;
  #pragma unroll
  for (int c = 0; c < 2; ++c) {
    s16x8 xv[8][2];
    #pragma unroll
    for (int k = 0; k < 8; ++k) {          // 16 loads issued back-to-back
      const short* xr = Xr + (long)ik[c * 8 + k] * 1024 + h0;
      xv[k][0] = *(const s16x8*)xr;
      xv[k][1] = *(const s16x8*)(xr + 8);
    }
    #pragma unroll
    for (int k = 0; k < 8; ++k) {
      union { s16x8 s; bf16x8 b; } u0, u1;
      u0.s = xv[k][0]; u1.s = xv[k][1];
      float akk = ak[c * 8 + k];
      #pragma unroll
      for (int t = 0; t < 8; ++t) {
        acc[t]     += akk * (float)u0.b[t];
        acc[8 + t] += akk * (float)u1.b[t];
      }
    }
  }
  short* er = p.erb + (long)be * 1024 + h0;
  *(s16x8*)er       = cvt8(acc);
  *(s16x8*)(er + 8) = cvt8(acc + 8);
  float c = 0.f;
  const float* brp = p.br + h0;
  #pragma unroll
  for (int t = 0; t < 16; ++t) c += acc[t] * brp[t];
  #pragma unroll
  for (int off = 32; off > 0; off >>= 1) c += __shfl_down(c, off);
  if (lane == 0) p.cf[be] = c;
}

// == k1: vu gate (0-255) | s_wT (256-511) | U (512-767) | Wo1 cvt (768-831) ==
__global__ __launch_bounds__(256) void k1(Params p) {
  __shared__ short lds[32768];   // 64 KB
  __shared__ float red[64];
  const int blk = blockIdx.x;
  if (blk < 256) {
    vu_ring(blk & 63, blk >> 6, p, lds, red);
  } else if (blk < 512) {
    int q = blk - 256;
    g64<16, 0>(p.Wrb, 512, p.rmb, 512, p.swTb, 1024,
               (q >> 4) * 64, (q & 15) * 64, nullptr, nullptr, nullptr, nullptr, lds);
  } else if (blk < 768) {
    int q = blk - 512;
    g64<16, 0>(p.Wo2b, 512, p.rmb, 512, p.Ub, 1024,
               (q >> 4) * 64, (q & 15) * 64, nullptr, nullptr, nullptr, nullptr, lds);
  } else {
    // Wo1 f32 -> bf16 (consumed by k2): 1,048,576 floats = 131072 vec8 units
    int g = (blk - 768) * 256 + threadIdx.x;   // 16384 threads, 8 units each
    #pragma unroll
    for (int it = 0; it < 8; ++it) {
      long o = ((long)(g + it * 16384)) * 8;
      const float* src = p.Wo + (o >> 10) * 1536 + (o & 1023);
      float t[8];
      *(float4*)t       = *(const float4*)src;
      *(float4*)(t + 4) = *(const float4*)(src + 4);
      *(s16x8*)(p.Wo1b + o) = cvt8(t);
    }
  }
}

// ==== k2: Weff = Wo1 + U@s_wT^T (0-255) | gw2 + softmax (256-511) ====
__global__ __launch_bounds__(256) void k2(Params p) {
  __shared__ short lds[32768];
  const int blk = blockIdx.x;
  if (blk < 256) {
    g64<32, 1>(p.Ub, 1024, p.swTb, 1024, p.Weffb, 1024,
               (blk >> 4) * 64, (blk & 15) * 64, p.Wo1b, nullptr, nullptr, nullptr, lds);
  } else {
    int q = blk - 256;
    int wave = threadIdx.x >> 6;
    gw2_wave(q * 4 + wave, p);
    entity_wave(q * 4 + wave, p);
  }
}

// ================= k3: out = er @ Weff^T + bo + cf*gw2 =================
__global__ __launch_bounds__(256) void k3(Params p) {
  __shared__ short lds[32768];
  const int blk = blockIdx.x;
  g64<32, 2>(p.erb, 1024, p.Weffb, 1024, p.out, 1024,
             (blk >> 4) * 64, (blk & 15) * 64, nullptr, p.bo, p.cf, p.gw2, lds);
}

extern "C" void kernel_launch(void* const* d_in, const int* in_sizes, int n_in,
                              void* d_out, int out_size, void* d_ws, size_t ws_size,
                              hipStream_t stream) {
  (void)in_sizes; (void)n_in; (void)out_size; (void)ws_size;
  Params p;
  p.ment = (const float*)d_in[0];
  p.ents = (const int*)d_in[1];
  p.msk  = (const int*)d_in[2];
  p.rm   = (const float*)d_in[3];
  p.Wv   = (const float*)d_in[4];
  p.bv   = (const float*)d_in[5];
  p.Wu   = (const float*)d_in[6];
  p.bu   = (const float*)d_in[7];
  p.Wa   = (const float*)d_in[8];
  // d_in[9] = ba: drops out (softmax shift-invariance)
  p.Wr   = (const float*)d_in[10];
  p.br   = (const float*)d_in[11];
  p.Wo   = (const float*)d_in[12];
  p.bo   = (const float*)d_in[13];
  p.out  = (float*)d_out;

  char* w = (char*)d_ws;
  auto alloc = [&](size_t bytes) {
    void* q = (void*)w; w += (bytes + 255) & ~(size_t)255; return q;
  };
  p.Xb    = (short*)alloc((size_t)2048 * 1024 * 2);  // X bf16
  p.Wvb   = (short*)alloc((size_t)256 * 1024 * 2);
  p.Wub   = (short*)alloc((size_t)256 * 1024 * 2);
  p.rmb   = (short*)alloc((size_t)1024 * 512 * 2);
  p.Wrb   = (short*)alloc((size_t)1024 * 512 * 2);
  p.Wo2b  = (short*)alloc((size_t)1024 * 512 * 2);
  p.Wo1b  = (short*)alloc((size_t)1024 * 1024 * 2);  // Wo1 bf16 (dense)
  p.swTb  = (short*)alloc((size_t)1024 * 1024 * 2);  // s_wT[h,r] bf16
  p.Ub    = (short*)alloc((size_t)1024 * 1024 * 2);  // U[h,r] bf16
  p.Weffb = (short*)alloc((size_t)1024 * 1024 * 2);  // Wo1 + U@s_wT^T bf16
  p.erb   = (short*)alloc((size_t)1024 * 1024 * 2);  // entity reprs bf16
  p.wpart = (float*)alloc((size_t)4 * 2048 * 4);     // gate partials
  p.cf    = (float*)alloc((size_t)1024 * 4);         // er . br
  p.gw2   = (float*)alloc((size_t)1024 * 4);         // rowsum(U)

  k0<<<512, 256, 0, stream>>>(p);
  k1<<<832, 256, 0, stream>>>(p);
  k2<<<512, 256, 0, stream>>>(p);
  k3<<<256, 256, 0, stream>>>(p);
}